// Round 10
// baseline (122.530 us; speedup 1.0000x reference)
//
#include <hip/hip_runtime.h>

#define NN 8192
#define TT 1024
#define WW 64
#define HH 256
#define NPB 8
#define DTF (1.0f/24.0f)

__device__ __forceinline__ float sigmoidf_(float v) { return 1.0f / (1.0f + __expf(-v)); }

// ---------------- MLP -> (k, xw) -> IRF[n][64] in ws ----------------
__global__ __launch_bounds__(256) void mlp_kernel(
    const float* __restrict__ phys,
    const float* __restrict__ w1, const float* __restrict__ b1,
    const float* __restrict__ w2, const float* __restrict__ b2,
    const float* __restrict__ w3, const float* __restrict__ b3,
    float* __restrict__ irf)
{
    const int n0 = blockIdx.x * NPB;
    const int j  = threadIdx.x;

    __shared__ float s_phys[NPB * 3];
    __shared__ __align__(16) float s_h1[NPB * HH];   // 8 KB
    __shared__ float s_red[4][NPB][2];
    __shared__ float s_kxw[NPB][2];

    if (j < NPB * 3) s_phys[j] = phys[n0 * 3 + j];
    __syncthreads();

    const float w1v0 = w1[j], w1v1 = w1[HH + j], w1v2 = w1[2 * HH + j], b1v = b1[j];
#pragma unroll
    for (int m = 0; m < NPB; ++m) {
        float h = s_phys[m*3+0] * w1v0 + s_phys[m*3+1] * w1v1 + s_phys[m*3+2] * w1v2 + b1v;
        s_h1[m * HH + j] = fmaxf(h, 0.0f);
    }
    __syncthreads();

    float acc[NPB];
#pragma unroll
    for (int m = 0; m < NPB; ++m) acc[m] = 0.0f;
#pragma unroll 4
    for (int i4 = 0; i4 < HH / 4; ++i4) {
        const int i = i4 * 4;
        const float wv0 = w2[(i + 0) * HH + j];
        const float wv1 = w2[(i + 1) * HH + j];
        const float wv2 = w2[(i + 2) * HH + j];
        const float wv3 = w2[(i + 3) * HH + j];
#pragma unroll
        for (int m = 0; m < NPB; ++m) {
            const float4 h4 = *(const float4*)&s_h1[m * HH + i];
            acc[m] += h4.x * wv0 + h4.y * wv1 + h4.z * wv2 + h4.w * wv3;
        }
    }

    const float b2v = b2[j];
    const float w30 = w3[j * 2 + 0], w31 = w3[j * 2 + 1];
    const int wv = j >> 6;

#pragma unroll
    for (int m = 0; m < NPB; ++m) {
        const float h2 = fmaxf(acc[m] + b2v, 0.0f);
        float r0 = h2 * w30;
        float r1 = h2 * w31;
#pragma unroll
        for (int o = 32; o >= 1; o >>= 1) {
            r0 += __shfl_xor(r0, o);
            r1 += __shfl_xor(r1, o);
        }
        if ((j & 63) == 0) { s_red[wv][m][0] = r0; s_red[wv][m][1] = r1; }
    }
    __syncthreads();

    if (j < NPB * 2) {
        const int m = j >> 1, d = j & 1;
        float raw = s_red[0][m][d] + s_red[1][m][d] + s_red[2][m][d] + s_red[3][m][d] + b3[d];
        float p;
        if (d == 0) p = sigmoidf_(raw) * 0.25f + 0.005f;          // k
        else        p = sigmoidf_(raw - 3.0f) * 1.2f;             // xw
        s_kxw[m][d] = p;
    }
    __syncthreads();

    {
        const int m = j >> 5, l = j & 31;
        const float k  = s_kxw[m][0];
        const float xw = s_kxw[m][1];
        const float delay = k * xw;
        const float tau   = fmaxf(k * (1.0f - xw), 0.5f * DTF);
        const float t0f = l * DTF, t1f = (l + 32) * DTF;
        float h0 = (t0f >= delay) ? __expf(-(t0f - delay) / tau) / tau : 0.0f;
        float h1 = (t1f >= delay) ? __expf(-(t1f - delay) / tau) / tau : 0.0f;
        float s = h0 + h1;
#pragma unroll
        for (int o = 16; o >= 1; o >>= 1) s += __shfl_xor(s, o);
        const float inv = 1.0f / (s + 1e-8f);
        float* dst = irf + (size_t)(n0 + m) * WW;
        dst[l]      = h0 * inv;
        dst[l + 32] = h1 * inv;
    }
}

// ---------------- conv helpers (full row, one wave, 16 outputs/thread) ----------------
__device__ __forceinline__ void load_rf(const float* __restrict__ irf, int n, float (&rf)[WW]) {
    const float* irp = irf + (size_t)n * WW;
#pragma unroll
    for (int i = 0; i < WW / 4; ++i) {
        const float4 f = *(const float4*)&irp[4 * i];
        rf[4*i+0] = f.x; rf[4*i+1] = f.y; rf[4*i+2] = f.z; rf[4*i+3] = f.w;
    }
}

// causal 64-tap conv of a wave-distributed row (lane owns a[16] consecutive),
// zeros before row start; halo via lane shuffles (no LDS).
__device__ __forceinline__ void wave_conv16(const float (&a)[16], const float (&rf)[WW],
                                            float (&y)[16], int tid)
{
#pragma unroll
    for (int j = 0; j < 16; ++j) y[j] = 0.0f;

#pragma unroll
    for (int m = 0; m < 16; ++m)
#pragma unroll
        for (int j = m; j < 16; ++j)
            y[j] += rf[j - m] * a[m];

#pragma unroll
    for (int d = 1; d <= 4; ++d) {
        float h[16];
#pragma unroll
        for (int m = 0; m < 16; ++m) {
            const float ha = __shfl(a[m], tid - d);
            h[m] = (tid >= d) ? ha : 0.0f;
        }
        if (d < 4) {
#pragma unroll
            for (int m = 0; m < 16; ++m)
#pragma unroll
                for (int j = 0; j < 16; ++j)
                    y[j] += rf[j + 16 * d - m] * h[m];
        } else {
#pragma unroll
            for (int m = 1; m < 16; ++m)
#pragma unroll
                for (int j = 0; j < m; ++j)
                    y[j] += rf[j + WW - m] * h[m];
        }
    }
}

__device__ __forceinline__ void load_row16(const float* __restrict__ p, int loc, float (&a)[16]) {
#pragma unroll
    for (int u = 0; u < 4; ++u) {
        const float4 v = *(const float4*)&p[loc + 4 * u];
        a[4*u+0] = v.x; a[4*u+1] = v.y; a[4*u+2] = v.z; a[4*u+3] = v.w;
    }
}

__device__ __forceinline__ void store_row16(float* __restrict__ p, int loc, const float (&y)[16]) {
#pragma unroll
    for (int u = 0; u < 4; ++u)
        *(float4*)&p[loc + 4 * u] = make_float4(y[4*u+0], y[4*u+1], y[4*u+2], y[4*u+3]);
}

// ---------------- merged: all leaves + L6-internal (child-recompute) ----------------
// Tasks 0..1365: L6-internal rows (n=1365+idx/2). Children are leaves -> recompute
// their convs inline from x (no dependency on leaf results; fat tasks first).
// Tasks 1366..13653: leaf rows (n=2048+idx/2), out[n] = irf_n (x) x[n].
__global__ __launch_bounds__(256) void route_leaf_l6(
    const float* __restrict__ x, const float* __restrict__ irf,
    float* __restrict__ out)
{
    const int wid = threadIdx.x >> 6;
    const int tid = threadIdx.x & 63;
    const int r   = blockIdx.x * 4 + wid;
    if (r >= 13654) return;

    const int loc = tid * 16;
    float rf[WW], a[16], y[16];

    if (r < 1366) {
        // L6 internal: acc = x[n] + sum_c irf_c (x) x[c]  (c are leaves; node 2047's
        // 4th child 8192 is OOB -> check)
        const int b = r & 1;
        const int n = __builtin_amdgcn_readfirstlane(1365 + (r >> 1));
        const size_t rowb = ((size_t)b * NN + n) * TT;
        const int c0 = 4 * n + 1;

        float acc[16];
        load_row16(x, (int)(rowb) + loc, acc);   // x row (rowb fits in 32b? 2*8192*1024 = 16M floats -> yes)
#pragma unroll 1
        for (int e = 0; e < 4; ++e) {
            const int c = c0 + e;
            if (c < NN) {
                load_row16(x + ((size_t)b * NN + c) * TT, loc, a);
                load_rf(irf, c, rf);
                wave_conv16(a, rf, y, tid);
#pragma unroll
                for (int q = 0; q < 16; ++q) acc[q] += y[q];
            }
        }
        load_rf(irf, n, rf);
        wave_conv16(acc, rf, y, tid);
        store_row16(out, (int)(rowb) + loc, y);
    } else {
        const int idx = r - 1366;
        const int b = idx & 1;
        const int n = __builtin_amdgcn_readfirstlane(2048 + (idx >> 1));
        const size_t rowb = ((size_t)b * NN + n) * TT;

        load_row16(x + rowb, loc, a);
        load_rf(irf, n, rf);
        wave_conv16(a, rf, y, tid);
        store_row16(out + rowb, loc, y);
    }
}

// ---------------- mid level: one wave per row, children read from out ----------------
__global__ __launch_bounds__(256) void route_mid(
    const float* __restrict__ x, const float* __restrict__ irf,
    float* __restrict__ out, int base, int n_tasks)
{
    const int wid = threadIdx.x >> 6;
    const int tid = threadIdx.x & 63;
    const int r   = blockIdx.x * 4 + wid;
    if (r >= n_tasks) return;

    const int b = r & 1;
    const int n = __builtin_amdgcn_readfirstlane(base + (r >> 1));
    const size_t rowb = ((size_t)b * NN + n) * TT;
    const int loc = tid * 16;
    const int c0  = 4 * n + 1;

    float a[16];
#pragma unroll
    for (int u = 0; u < 4; ++u) {
        float4 v = *(const float4*)&x[rowb + loc + 4 * u];
#pragma unroll
        for (int e = 0; e < 4; ++e) {
            const float4 w = *(const float4*)&out[((size_t)b * NN + c0 + e) * TT + loc + 4 * u];
            v.x += w.x; v.y += w.y; v.z += w.z; v.w += w.w;
        }
        a[4*u+0] = v.x; a[4*u+1] = v.y; a[4*u+2] = v.z; a[4*u+3] = v.w;
    }

    float rf[WW], y[16];
    load_rf(irf, n, rf);
    wave_conv16(a, rf, y, tid);
    store_row16(out + rowb, loc, y);
}

// ---------------- 3-level subtree, block-local fusion ----------------
// Block owns top node p (= top_base + blockIdx/2, batch = blockIdx&1).
// Wave w owns child cw=4p+1+w. Phase A: 4 grandchildren of cw (read their child
// outs from global). Phase B: conv child row from LDS acc. Phase C: wave 0 convs p.
// All nodes have 4 valid in-range children (top_base = 5 -> p in L2).
__global__ __launch_bounds__(256) void route_tail3(
    const float* __restrict__ x, const float* __restrict__ irf,
    float* __restrict__ out, int top_base)
{
    const int wid = threadIdx.x >> 6;
    const int tid = threadIdx.x & 63;
    const int b   = blockIdx.x & 1;
    const int p   = top_base + (int)(blockIdx.x >> 1);

    __shared__ __align__(16) float s_ch[4][TT];   // 16 KB

    const int cw = 4 * p + 1 + wid;
    const size_t crow = ((size_t)b * NN + cw) * TT;
    const int loc = tid * 16;

#pragma unroll
    for (int u = 0; u < 4; ++u)
        *(float4*)&s_ch[wid][loc + 4 * u] = *(const float4*)&x[crow + loc + 4 * u];

    float rf[WW], a[16], y[16];

    // phase A: grandchildren g (children of cw); g's children read from out
#pragma unroll 1
    for (int k = 0; k < 4; ++k) {
        const int g = 4 * cw + 1 + k;
        const size_t grow = ((size_t)b * NN + g) * TT;
#pragma unroll
        for (int u = 0; u < 4; ++u) {
            float4 v = *(const float4*)&x[grow + loc + 4 * u];
#pragma unroll
            for (int e = 0; e < 4; ++e) {
                const float4 w = *(const float4*)&out[((size_t)b * NN + (4 * g + 1 + e)) * TT + loc + 4 * u];
                v.x += w.x; v.y += w.y; v.z += w.z; v.w += w.w;
            }
            a[4*u+0] = v.x; a[4*u+1] = v.y; a[4*u+2] = v.z; a[4*u+3] = v.w;
        }
        load_rf(irf, g, rf);
        wave_conv16(a, rf, y, tid);
#pragma unroll
        for (int u = 0; u < 4; ++u) {
            *(float4*)&out[grow + loc + 4 * u] = make_float4(y[4*u+0], y[4*u+1], y[4*u+2], y[4*u+3]);
#pragma unroll
            for (int e = 0; e < 4; ++e) s_ch[wid][loc + 4*u + e] += y[4*u + e];
        }
    }

    // phase B: child row
#pragma unroll
    for (int u = 0; u < 4; ++u) {
        const float4 v = *(const float4*)&s_ch[wid][loc + 4 * u];
        a[4*u+0] = v.x; a[4*u+1] = v.y; a[4*u+2] = v.z; a[4*u+3] = v.w;
    }
    load_rf(irf, cw, rf);
    wave_conv16(a, rf, y, tid);
#pragma unroll
    for (int u = 0; u < 4; ++u) {
        const float4 f = make_float4(y[4*u+0], y[4*u+1], y[4*u+2], y[4*u+3]);
        *(float4*)&out[crow + loc + 4 * u] = f;
        *(float4*)&s_ch[wid][loc + 4 * u]  = f;
    }

    __syncthreads();

    // phase C: wave 0 computes p
    if (wid == 0) {
        const size_t prow = ((size_t)b * NN + p) * TT;
#pragma unroll
        for (int u = 0; u < 4; ++u) {
            float4 v = *(const float4*)&x[prow + loc + 4 * u];
#pragma unroll
            for (int w2 = 0; w2 < 4; ++w2) {
                const float4 cc = *(const float4*)&s_ch[w2][loc + 4 * u];
                v.x += cc.x; v.y += cc.y; v.z += cc.z; v.w += cc.w;
            }
            a[4*u+0] = v.x; a[4*u+1] = v.y; a[4*u+2] = v.z; a[4*u+3] = v.w;
        }
        load_rf(irf, p, rf);
        wave_conv16(a, rf, y, tid);
#pragma unroll
        for (int u = 0; u < 4; ++u)
            *(float4*)&out[prow + loc + 4 * u] = make_float4(y[4*u+0], y[4*u+1], y[4*u+2], y[4*u+3]);
    }
}

// ---------------- final: L1 rows (children from out) + root ----------------
__global__ __launch_bounds__(256) void route_tail2(
    const float* __restrict__ x, const float* __restrict__ irf,
    float* __restrict__ out)
{
    const int wid = threadIdx.x >> 6;
    const int tid = threadIdx.x & 63;
    const int b   = blockIdx.x;          // 2 blocks

    __shared__ __align__(16) float s_ch[4][TT];

    const int cw = 1 + wid;              // L1
    const size_t crow = ((size_t)b * NN + cw) * TT;
    const int loc = tid * 16;

    float rf[WW], a[16], y[16];

    // L1 row: x + children (L2, 5..20) from out
#pragma unroll
    for (int u = 0; u < 4; ++u) {
        float4 v = *(const float4*)&x[crow + loc + 4 * u];
#pragma unroll
        for (int e = 0; e < 4; ++e) {
            const float4 w = *(const float4*)&out[((size_t)b * NN + (4 * cw + 1 + e)) * TT + loc + 4 * u];
            v.x += w.x; v.y += w.y; v.z += w.z; v.w += w.w;
        }
        a[4*u+0] = v.x; a[4*u+1] = v.y; a[4*u+2] = v.z; a[4*u+3] = v.w;
    }
    load_rf(irf, cw, rf);
    wave_conv16(a, rf, y, tid);
#pragma unroll
    for (int u = 0; u < 4; ++u) {
        const float4 f = make_float4(y[4*u+0], y[4*u+1], y[4*u+2], y[4*u+3]);
        *(float4*)&out[crow + loc + 4 * u] = f;
        *(float4*)&s_ch[wid][loc + 4 * u]  = f;
    }

    __syncthreads();

    if (wid == 0) {
        const size_t prow = (size_t)b * NN * TT;     // node 0
#pragma unroll
        for (int u = 0; u < 4; ++u) {
            float4 v = *(const float4*)&x[prow + loc + 4 * u];
#pragma unroll
            for (int w2 = 0; w2 < 4; ++w2) {
                const float4 cc = *(const float4*)&s_ch[w2][loc + 4 * u];
                v.x += cc.x; v.y += cc.y; v.z += cc.z; v.w += cc.w;
            }
            a[4*u+0] = v.x; a[4*u+1] = v.y; a[4*u+2] = v.z; a[4*u+3] = v.w;
        }
        load_rf(irf, 0, rf);
        wave_conv16(a, rf, y, tid);
#pragma unroll
        for (int u = 0; u < 4; ++u)
            *(float4*)&out[prow + loc + 4 * u] = make_float4(y[4*u+0], y[4*u+1], y[4*u+2], y[4*u+3]);
    }
}

extern "C" void kernel_launch(void* const* d_in, const int* in_sizes, int n_in,
                              void* d_out, int out_size, void* d_ws, size_t ws_size,
                              hipStream_t stream) {
    const float* x    = (const float*)d_in[0];
    const float* phys = (const float*)d_in[1];
    const float* w1   = (const float*)d_in[2];
    const float* b1   = (const float*)d_in[3];
    const float* w2   = (const float*)d_in[4];
    const float* b2   = (const float*)d_in[5];
    const float* w3   = (const float*)d_in[6];
    const float* b3   = (const float*)d_in[7];
    // d_in[8] = parent, d_in[9] = depth: fixed 4-ary heap tree (children 4n+1..4n+4)

    float* out = (float*)d_out;
    float* irf = (float*)d_ws;   // N*64 floats = 2 MB

    mlp_kernel<<<NN / NPB, 256, 0, stream>>>(phys, w1, b1, w2, b2, w3, b3, irf);

    // 1) leaves (12288 rows) + L6-internal (1366 rows, child-recompute), one dispatch
    route_leaf_l6<<<(13654 + 3) / 4, 256, 0, stream>>>(x, irf, out);
    // 2) L5: 1024 nodes x 2 = 2048 rows (children = L6 outs)
    route_mid<<<(2048 + 3) / 4, 256, 0, stream>>>(x, irf, out, 341, 2048);
    // 3) L4+L3+L2 fused per L2 node: 16 x 2 = 32 blocks
    route_tail3<<<32, 256, 0, stream>>>(x, irf, out, 5);
    // 4) L1+L0: 2 blocks
    route_tail2<<<2, 256, 0, stream>>>(x, irf, out);
}

// Round 11
// 97.489 us; speedup vs baseline: 1.2569x; 1.2569x over previous
//
#include <hip/hip_runtime.h>
#include <hip/hip_bf16.h>

#define NN 8192
#define TT 1024
#define WW 64
#define HH 256
#define NPB 8
#define DTF (1.0f/24.0f)

typedef __attribute__((ext_vector_type(8))) short short8_t;   // 8 bf16 (4 VGPR)
typedef __attribute__((ext_vector_type(4))) float f32x4_t;

__device__ __forceinline__ float sigmoidf_(float v) { return 1.0f / (1.0f + __expf(-v)); }

__device__ __forceinline__ short f2bf(float f) {
    __hip_bfloat16 h = __float2bfloat16(f);
    short s; __builtin_memcpy(&s, &h, sizeof(short));
    return s;
}

// LDS element-index swizzle: fold row bits 6,7 into bank bits 3,4 (involution,
// keeps 8-short granules intact -> b128 stays aligned; 4-way -> 2-way = free)
__device__ __forceinline__ int swz(int e) { return e ^ (((e >> 6) & 3) << 3); }

// ---------------- MLP -> (k, xw) -> IRF[n][64] in ws ----------------
__global__ __launch_bounds__(256) void mlp_kernel(
    const float* __restrict__ phys,
    const float* __restrict__ w1, const float* __restrict__ b1,
    const float* __restrict__ w2, const float* __restrict__ b2,
    const float* __restrict__ w3, const float* __restrict__ b3,
    float* __restrict__ irf)
{
    const int n0 = blockIdx.x * NPB;
    const int j  = threadIdx.x;

    __shared__ float s_phys[NPB * 3];
    __shared__ __align__(16) float s_h1[NPB * HH];
    __shared__ float s_red[4][NPB][2];
    __shared__ float s_kxw[NPB][2];

    if (j < NPB * 3) s_phys[j] = phys[n0 * 3 + j];
    __syncthreads();

    const float w1v0 = w1[j], w1v1 = w1[HH + j], w1v2 = w1[2 * HH + j], b1v = b1[j];
#pragma unroll
    for (int m = 0; m < NPB; ++m) {
        float h = s_phys[m*3+0] * w1v0 + s_phys[m*3+1] * w1v1 + s_phys[m*3+2] * w1v2 + b1v;
        s_h1[m * HH + j] = fmaxf(h, 0.0f);
    }
    __syncthreads();

    float acc[NPB];
#pragma unroll
    for (int m = 0; m < NPB; ++m) acc[m] = 0.0f;
#pragma unroll 4
    for (int i4 = 0; i4 < HH / 4; ++i4) {
        const int i = i4 * 4;
        const float wv0 = w2[(i + 0) * HH + j];
        const float wv1 = w2[(i + 1) * HH + j];
        const float wv2 = w2[(i + 2) * HH + j];
        const float wv3 = w2[(i + 3) * HH + j];
#pragma unroll
        for (int m = 0; m < NPB; ++m) {
            const float4 h4 = *(const float4*)&s_h1[m * HH + i];
            acc[m] += h4.x * wv0 + h4.y * wv1 + h4.z * wv2 + h4.w * wv3;
        }
    }

    const float b2v = b2[j];
    const float w30 = w3[j * 2 + 0], w31 = w3[j * 2 + 1];
    const int wv = j >> 6;

#pragma unroll
    for (int m = 0; m < NPB; ++m) {
        const float h2 = fmaxf(acc[m] + b2v, 0.0f);
        float r0 = h2 * w30;
        float r1 = h2 * w31;
#pragma unroll
        for (int o = 32; o >= 1; o >>= 1) {
            r0 += __shfl_xor(r0, o);
            r1 += __shfl_xor(r1, o);
        }
        if ((j & 63) == 0) { s_red[wv][m][0] = r0; s_red[wv][m][1] = r1; }
    }
    __syncthreads();

    if (j < NPB * 2) {
        const int m = j >> 1, d = j & 1;
        float raw = s_red[0][m][d] + s_red[1][m][d] + s_red[2][m][d] + s_red[3][m][d] + b3[d];
        float p;
        if (d == 0) p = sigmoidf_(raw) * 0.25f + 0.005f;
        else        p = sigmoidf_(raw - 3.0f) * 1.2f;
        s_kxw[m][d] = p;
    }
    __syncthreads();

    {
        const int m = j >> 5, l = j & 31;
        const float k  = s_kxw[m][0];
        const float xw = s_kxw[m][1];
        const float delay = k * xw;
        const float tau   = fmaxf(k * (1.0f - xw), 0.5f * DTF);
        const float t0f = l * DTF, t1f = (l + 32) * DTF;
        float h0 = (t0f >= delay) ? __expf(-(t0f - delay) / tau) / tau : 0.0f;
        float h1 = (t1f >= delay) ? __expf(-(t1f - delay) / tau) / tau : 0.0f;
        float s = h0 + h1;
#pragma unroll
        for (int o = 16; o >= 1; o >>= 1) s += __shfl_xor(s, o);
        const float inv = 1.0f / (s + 1e-8f);
        float* dst = irf + (size_t)(n0 + m) * WW;
        dst[l]      = h0 * inv;
        dst[l + 32] = h1 * inv;
    }
}

// ================= MFMA conv machinery =================
// Row conv as 12x mfma_f32_16x16x32_bf16: Y[16S+r][c] = sum_p sum_kk A[16(16S+r)
// -16(2p+1)+kk] * B_p[kk][c], B_p[kk][c] = rfz[c-kk+16+32p]. LDS holds the row
// as bf16 with an 80-elem zero prologue (causal left edge), swizzled.
// A-frag: row=lane&15, k=8*(lane>>4)+j ; B-frag: col=lane&15, k=8*(lane>>4)+j ;
// D: col=lane&15, row=4*(lane>>4)+q  (m89-verified).

#define LROW 1152   // 80 prologue + 1024 row (+pad), shorts

// zero prologue [0,80)
__device__ __forceinline__ void zero_prologue(short* sab, int tid) {
    if (tid < 10) {
        short8_t z = {0,0,0,0,0,0,0,0};
        *(short8_t*)&sab[swz(8 * tid)] = z;
    }
}

__device__ __forceinline__ void load16(const float* __restrict__ src, int tid, float (&a)[16]) {
#pragma unroll
    for (int u = 0; u < 4; ++u) {
        const float4 v = *(const float4*)&src[16 * tid + 4 * u];
        a[4*u+0] = v.x; a[4*u+1] = v.y; a[4*u+2] = v.z; a[4*u+3] = v.w;
    }
}

// lane t stages row elements 16t..16t+15 as bf16 into LDS [80+16t ...]
__device__ __forceinline__ void stage16(short* sab, const float (&a)[16], int tid) {
#pragma unroll
    for (int u = 0; u < 2; ++u) {
        short8_t s;
#pragma unroll
        for (int j = 0; j < 8; ++j) s[j] = f2bf(a[8*u + j]);
        *(short8_t*)&sab[swz(80 + 16 * tid + 8 * u)] = s;
    }
}

__device__ __forceinline__ void build_bfrags(const float* __restrict__ irp,
                                             int lc, int lg, short8_t (&bf)[3]) {
#pragma unroll
    for (int p = 0; p < 3; ++p) {
        short8_t v;
#pragma unroll
        for (int j = 0; j < 8; ++j) {
            const int idx = lc - 8 * lg - j + 16 + 32 * p;
            const float t = irp[idx & 63];
            v[j] = f2bf((idx >= 0 && idx < 64) ? t : 0.0f);
        }
        bf[p] = v;
    }
}

// 12 MFMAs accumulating into acc[S]; EB = 80 + 16*(lane&15) + 8*(lane>>4)
__device__ __forceinline__ void conv_mfma(const short* sab, const short8_t (&bf)[3],
                                          int EB, f32x4_t (&acc)[4]) {
#pragma unroll
    for (int S = 0; S < 4; ++S) {
#pragma unroll
        for (int p = 0; p < 3; ++p) {
            const short8_t af = *(const short8_t*)&sab[swz(EB + 256 * S - 16 * (2 * p + 1))];
            acc[S] = __builtin_amdgcn_mfma_f32_16x16x32_bf16(af, bf[p], acc[S], 0, 0, 0);
        }
    }
}

// ---------------- leaves 2048..5460 + L6-internal 1365..2047 ----------------
// Tasks 0..1365: L6-int node n=1365+(r>>1): computes AND stores its 4 leaf
// children (5461..8191) via D-layout register accumulation, then out[n].
// Tasks 1366..8191: leaf node n=2048+(idx>>1) (children of mid nodes).
__global__ __launch_bounds__(256) void route_lf6_mfma(
    const float* __restrict__ x, const float* __restrict__ irf,
    float* __restrict__ out)
{
    const int wid = threadIdx.x >> 6;
    const int tid = threadIdx.x & 63;
    const int r   = blockIdx.x * 4 + wid;

    const int lc = tid & 15, lg = tid >> 4;
    const int EB = 80 + 16 * lc + 8 * lg;

    __shared__ __align__(16) short s_a[4][LROW];
    short* sab = s_a[wid];
    zero_prologue(sab, tid);

    float a16[16];
    short8_t bf[3];

    if (r < 1366) {
        const int b = r & 1;
        const int n = __builtin_amdgcn_readfirstlane(1365 + (r >> 1));
        const size_t rowb = ((size_t)b * NN + n) * TT;
        const int c0 = 4 * n + 1;

        // accD = x[n] in D-layout
        f32x4_t accD[4];
#pragma unroll
        for (int S = 0; S < 4; ++S)
#pragma unroll
            for (int q = 0; q < 4; ++q)
                accD[S][q] = x[rowb + 256 * S + 64 * lg + 16 * q + lc];

#pragma unroll 1
        for (int e = 0; e < 4; ++e) {
            const int c = c0 + e;
            if (c < NN) {            // node 2047: 4th child 8192 OOB
                const size_t crow = ((size_t)b * NN + c) * TT;
                load16(x + crow, tid, a16);
                stage16(sab, a16, tid);
                build_bfrags(irf + (size_t)c * WW, lc, lg, bf);
                f32x4_t accT[4];
#pragma unroll
                for (int S = 0; S < 4; ++S) accT[S] = f32x4_t{0.f, 0.f, 0.f, 0.f};
                conv_mfma(sab, bf, EB, accT);
#pragma unroll
                for (int S = 0; S < 4; ++S) {
#pragma unroll
                    for (int q = 0; q < 4; ++q)
                        out[crow + 256 * S + 64 * lg + 16 * q + lc] = accT[S][q];
                    accD[S] += accT[S];
                }
            }
        }

        // write accD row (bf16, D-layout scatter) and run the final conv
#pragma unroll
        for (int S = 0; S < 4; ++S)
#pragma unroll
            for (int q = 0; q < 4; ++q)
                sab[swz(80 + 256 * S + 64 * lg + 16 * q + lc)] = f2bf(accD[S][q]);

        build_bfrags(irf + (size_t)n * WW, lc, lg, bf);
        f32x4_t accF[4];
#pragma unroll
        for (int S = 0; S < 4; ++S) accF[S] = f32x4_t{0.f, 0.f, 0.f, 0.f};
        conv_mfma(sab, bf, EB, accF);
#pragma unroll
        for (int S = 0; S < 4; ++S)
#pragma unroll
            for (int q = 0; q < 4; ++q)
                out[rowb + 256 * S + 64 * lg + 16 * q + lc] = accF[S][q];
    } else {
        const int idx = r - 1366;
        const int b = idx & 1;
        const int n = __builtin_amdgcn_readfirstlane(2048 + (idx >> 1));
        const size_t rowb = ((size_t)b * NN + n) * TT;

        load16(x + rowb, tid, a16);
        stage16(sab, a16, tid);
        build_bfrags(irf + (size_t)n * WW, lc, lg, bf);
        f32x4_t accF[4];
#pragma unroll
        for (int S = 0; S < 4; ++S) accF[S] = f32x4_t{0.f, 0.f, 0.f, 0.f};
        conv_mfma(sab, bf, EB, accF);
#pragma unroll
        for (int S = 0; S < 4; ++S)
#pragma unroll
            for (int q = 0; q < 4; ++q)
                out[rowb + 256 * S + 64 * lg + 16 * q + lc] = accF[S][q];
    }
}

// ---------------- L5 (341..1364): acc = x + 4 child outs, one MFMA conv ----------------
__global__ __launch_bounds__(256) void route_mid_mfma(
    const float* __restrict__ x, const float* __restrict__ irf,
    float* __restrict__ out)
{
    const int wid = threadIdx.x >> 6;
    const int tid = threadIdx.x & 63;
    const int r   = blockIdx.x * 4 + wid;

    const int lc = tid & 15, lg = tid >> 4;
    const int EB = 80 + 16 * lc + 8 * lg;

    __shared__ __align__(16) short s_a[4][LROW];
    short* sab = s_a[wid];
    zero_prologue(sab, tid);

    const int b = r & 1;
    const int n = __builtin_amdgcn_readfirstlane(341 + (r >> 1));
    const size_t rowb = ((size_t)b * NN + n) * TT;
    const int c0 = 4 * n + 1;     // 1365..5460, all valid

    float a16[16];
#pragma unroll
    for (int u = 0; u < 4; ++u) {
        float4 v = *(const float4*)&x[rowb + 16 * tid + 4 * u];
#pragma unroll
        for (int e = 0; e < 4; ++e) {
            const float4 w = *(const float4*)&out[((size_t)b * NN + c0 + e) * TT + 16 * tid + 4 * u];
            v.x += w.x; v.y += w.y; v.z += w.z; v.w += w.w;
        }
        a16[4*u+0] = v.x; a16[4*u+1] = v.y; a16[4*u+2] = v.z; a16[4*u+3] = v.w;
    }
    stage16(sab, a16, tid);

    short8_t bf[3];
    build_bfrags(irf + (size_t)n * WW, lc, lg, bf);
    f32x4_t accF[4];
#pragma unroll
    for (int S = 0; S < 4; ++S) accF[S] = f32x4_t{0.f, 0.f, 0.f, 0.f};
    conv_mfma(sab, bf, EB, accF);
#pragma unroll
    for (int S = 0; S < 4; ++S)
#pragma unroll
        for (int q = 0; q < 4; ++q)
            out[rowb + 256 * S + 64 * lg + 16 * q + lc] = accF[S][q];
}

// ================= scalar fp32 tail (values too large for bf16) =================
__device__ __forceinline__ void load_rf(const float* __restrict__ irf, int n, float (&rf)[WW]) {
    const float* irp = irf + (size_t)n * WW;
#pragma unroll
    for (int i = 0; i < WW / 4; ++i) {
        const float4 f = *(const float4*)&irp[4 * i];
        rf[4*i+0] = f.x; rf[4*i+1] = f.y; rf[4*i+2] = f.z; rf[4*i+3] = f.w;
    }
}

__device__ __forceinline__ void wave_conv16(const float (&a)[16], const float (&rf)[WW],
                                            float (&y)[16], int tid)
{
#pragma unroll
    for (int j = 0; j < 16; ++j) y[j] = 0.0f;
#pragma unroll
    for (int m = 0; m < 16; ++m)
#pragma unroll
        for (int j = m; j < 16; ++j)
            y[j] += rf[j - m] * a[m];
#pragma unroll
    for (int d = 1; d <= 4; ++d) {
        float h[16];
#pragma unroll
        for (int m = 0; m < 16; ++m) {
            const float ha = __shfl(a[m], tid - d);
            h[m] = (tid >= d) ? ha : 0.0f;
        }
        if (d < 4) {
#pragma unroll
            for (int m = 0; m < 16; ++m)
#pragma unroll
                for (int j = 0; j < 16; ++j)
                    y[j] += rf[j + 16 * d - m] * h[m];
        } else {
#pragma unroll
            for (int m = 1; m < 16; ++m)
#pragma unroll
                for (int j = 0; j < m; ++j)
                    y[j] += rf[j + WW - m] * h[m];
        }
    }
}

// L4+L3+L2 fused per L2 node (top_base=5): 16x2 = 32 blocks
__global__ __launch_bounds__(256) void route_tail3(
    const float* __restrict__ x, const float* __restrict__ irf,
    float* __restrict__ out, int top_base)
{
    const int wid = threadIdx.x >> 6;
    const int tid = threadIdx.x & 63;
    const int b   = blockIdx.x & 1;
    const int p   = top_base + (int)(blockIdx.x >> 1);

    __shared__ __align__(16) float s_ch[4][TT];

    const int cw = 4 * p + 1 + wid;
    const size_t crow = ((size_t)b * NN + cw) * TT;
    const int loc = tid * 16;

#pragma unroll
    for (int u = 0; u < 4; ++u)
        *(float4*)&s_ch[wid][loc + 4 * u] = *(const float4*)&x[crow + loc + 4 * u];

    float rf[WW], a[16], y[16];

#pragma unroll 1
    for (int k = 0; k < 4; ++k) {
        const int g = 4 * cw + 1 + k;
        const size_t grow = ((size_t)b * NN + g) * TT;
#pragma unroll
        for (int u = 0; u < 4; ++u) {
            float4 v = *(const float4*)&x[grow + loc + 4 * u];
#pragma unroll
            for (int e = 0; e < 4; ++e) {
                const float4 w = *(const float4*)&out[((size_t)b * NN + (4 * g + 1 + e)) * TT + loc + 4 * u];
                v.x += w.x; v.y += w.y; v.z += w.z; v.w += w.w;
            }
            a[4*u+0] = v.x; a[4*u+1] = v.y; a[4*u+2] = v.z; a[4*u+3] = v.w;
        }
        load_rf(irf, g, rf);
        wave_conv16(a, rf, y, tid);
#pragma unroll
        for (int u = 0; u < 4; ++u) {
            *(float4*)&out[grow + loc + 4 * u] = make_float4(y[4*u+0], y[4*u+1], y[4*u+2], y[4*u+3]);
#pragma unroll
            for (int e = 0; e < 4; ++e) s_ch[wid][loc + 4*u + e] += y[4*u + e];
        }
    }

#pragma unroll
    for (int u = 0; u < 4; ++u) {
        const float4 v = *(const float4*)&s_ch[wid][loc + 4 * u];
        a[4*u+0] = v.x; a[4*u+1] = v.y; a[4*u+2] = v.z; a[4*u+3] = v.w;
    }
    load_rf(irf, cw, rf);
    wave_conv16(a, rf, y, tid);
#pragma unroll
    for (int u = 0; u < 4; ++u) {
        const float4 f = make_float4(y[4*u+0], y[4*u+1], y[4*u+2], y[4*u+3]);
        *(float4*)&out[crow + loc + 4 * u] = f;
        *(float4*)&s_ch[wid][loc + 4 * u]  = f;
    }

    __syncthreads();

    if (wid == 0) {
        const size_t prow = ((size_t)b * NN + p) * TT;
#pragma unroll
        for (int u = 0; u < 4; ++u) {
            float4 v = *(const float4*)&x[prow + loc + 4 * u];
#pragma unroll
            for (int w2 = 0; w2 < 4; ++w2) {
                const float4 cc = *(const float4*)&s_ch[w2][loc + 4 * u];
                v.x += cc.x; v.y += cc.y; v.z += cc.z; v.w += cc.w;
            }
            a[4*u+0] = v.x; a[4*u+1] = v.y; a[4*u+2] = v.z; a[4*u+3] = v.w;
        }
        load_rf(irf, p, rf);
        wave_conv16(a, rf, y, tid);
#pragma unroll
        for (int u = 0; u < 4; ++u)
            *(float4*)&out[prow + loc + 4 * u] = make_float4(y[4*u+0], y[4*u+1], y[4*u+2], y[4*u+3]);
    }
}

// L1 + root
__global__ __launch_bounds__(256) void route_tail2(
    const float* __restrict__ x, const float* __restrict__ irf,
    float* __restrict__ out)
{
    const int wid = threadIdx.x >> 6;
    const int tid = threadIdx.x & 63;
    const int b   = blockIdx.x;

    __shared__ __align__(16) float s_ch[4][TT];

    const int cw = 1 + wid;
    const size_t crow = ((size_t)b * NN + cw) * TT;
    const int loc = tid * 16;

    float rf[WW], a[16], y[16];

#pragma unroll
    for (int u = 0; u < 4; ++u) {
        float4 v = *(const float4*)&x[crow + loc + 4 * u];
#pragma unroll
        for (int e = 0; e < 4; ++e) {
            const float4 w = *(const float4*)&out[((size_t)b * NN + (4 * cw + 1 + e)) * TT + loc + 4 * u];
            v.x += w.x; v.y += w.y; v.z += w.z; v.w += w.w;
        }
        a[4*u+0] = v.x; a[4*u+1] = v.y; a[4*u+2] = v.z; a[4*u+3] = v.w;
    }
    load_rf(irf, cw, rf);
    wave_conv16(a, rf, y, tid);
#pragma unroll
    for (int u = 0; u < 4; ++u) {
        const float4 f = make_float4(y[4*u+0], y[4*u+1], y[4*u+2], y[4*u+3]);
        *(float4*)&out[crow + loc + 4 * u] = f;
        *(float4*)&s_ch[wid][loc + 4 * u]  = f;
    }

    __syncthreads();

    if (wid == 0) {
        const size_t prow = (size_t)b * NN * TT;
#pragma unroll
        for (int u = 0; u < 4; ++u) {
            float4 v = *(const float4*)&x[prow + loc + 4 * u];
#pragma unroll
            for (int w2 = 0; w2 < 4; ++w2) {
                const float4 cc = *(const float4*)&s_ch[w2][loc + 4 * u];
                v.x += cc.x; v.y += cc.y; v.z += cc.z; v.w += cc.w;
            }
            a[4*u+0] = v.x; a[4*u+1] = v.y; a[4*u+2] = v.z; a[4*u+3] = v.w;
        }
        load_rf(irf, 0, rf);
        wave_conv16(a, rf, y, tid);
#pragma unroll
        for (int u = 0; u < 4; ++u)
            *(float4*)&out[prow + loc + 4 * u] = make_float4(y[4*u+0], y[4*u+1], y[4*u+2], y[4*u+3]);
    }
}

extern "C" void kernel_launch(void* const* d_in, const int* in_sizes, int n_in,
                              void* d_out, int out_size, void* d_ws, size_t ws_size,
                              hipStream_t stream) {
    const float* x    = (const float*)d_in[0];
    const float* phys = (const float*)d_in[1];
    const float* w1   = (const float*)d_in[2];
    const float* b1   = (const float*)d_in[3];
    const float* w2   = (const float*)d_in[4];
    const float* b2   = (const float*)d_in[5];
    const float* w3   = (const float*)d_in[6];
    const float* b3   = (const float*)d_in[7];
    // d_in[8] = parent, d_in[9] = depth: fixed 4-ary heap tree (children 4n+1..4n+4)

    float* out = (float*)d_out;
    float* irf = (float*)d_ws;   // N*64 floats = 2 MB

    mlp_kernel<<<NN / NPB, 256, 0, stream>>>(phys, w1, b1, w2, b2, w3, b3, irf);

    // 1) L6-int (1366 tasks, stores children 5461..8191) + leaves 2048..5460
    //    (6826 tasks) = 8192 tasks exactly -> 2048 blocks
    route_lf6_mfma<<<2048, 256, 0, stream>>>(x, irf, out);
    // 2) L5: 1024 x 2 = 2048 tasks
    route_mid_mfma<<<512, 256, 0, stream>>>(x, irf, out);
    // 3) L4+L3+L2 fused per L2 node
    route_tail3<<<32, 256, 0, stream>>>(x, irf, out, 5);
    // 4) L1+L0
    route_tail2<<<2, 256, 0, stream>>>(x, irf, out);
}

// Round 13
// 89.378 us; speedup vs baseline: 1.3709x; 1.0908x over previous
//
#include <hip/hip_runtime.h>
#include <hip/hip_bf16.h>

#define NN 8192
#define TT 1024
#define WW 64
#define HH 256
#define DTF (1.0f/24.0f)

typedef __attribute__((ext_vector_type(8))) short short8_t;   // 8 bf16 (4 VGPR)
typedef __attribute__((ext_vector_type(4))) float f32x4_t;

__device__ __forceinline__ float sigmoidf_(float v) { return 1.0f / (1.0f + __expf(-v)); }

__device__ __forceinline__ short f2bf(float f) {
    __hip_bfloat16 h = __float2bfloat16(f);
    short s; __builtin_memcpy(&s, &h, sizeof(short));
    return s;
}

// LDS element-index swizzle (8-short granule, keeps b128 aligned)
__device__ __forceinline__ int swz(int e) { return e ^ (((e >> 6) & 3) << 3); }

// ---------------- w2 -> bf16 B-frag-ordered table (one-time) ----------------
// w2f[ks][nt][lane][j] = w2[ks*32 + 8*(lane>>4) + j][nt*16 + (lane&15)]
__global__ __launch_bounds__(256) void w2bf_kernel(
    const float* __restrict__ w2, short* __restrict__ w2f)
{
    const int gid  = blockIdx.x * 256 + threadIdx.x;   // 0..8191
    const int ks   = gid >> 10;
    const int rest = gid & 1023;
    const int nt   = rest >> 6;
    const int lane = rest & 63;
    const int lg = lane >> 4, lc = lane & 15;
    short8_t v;
#pragma unroll
    for (int j = 0; j < 8; ++j)
        v[j] = f2bf(w2[(ks * 32 + 8 * lg + j) * HH + nt * 16 + lc]);
    *(short8_t*)&w2f[(size_t)gid * 8] = v;
}

// ---------------- MLP (MFMA layer-2) -> (k,xw) -> IRF + conv B-frag table ----------------
// 512 blocks x 256 thr, 16 nodes/block. Layer2: 16x256 @ 256x256 bf16 MFMA.
__global__ __launch_bounds__(256) void mlp_mfma(
    const float* __restrict__ phys,
    const float* __restrict__ w1, const float* __restrict__ b1,
    const short* __restrict__ w2f, const float* __restrict__ b2,
    const float* __restrict__ w3, const float* __restrict__ b3,
    float* __restrict__ irf, short* __restrict__ irfB)
{
    const int t    = threadIdx.x;
    const int wv   = t >> 6;
    const int lane = t & 63;
    const int lc = lane & 15, lg = lane >> 4;
    const int n0 = blockIdx.x * 16;

    __shared__ float s_phys[16 * 3];
    __shared__ __align__(16) short s_h1b[16 * 256];   // 8KB, swizzled bf16
    __shared__ float s_red[4][16][2];
    __shared__ float s_kxw[16][2];
    __shared__ __align__(16) float s_irf[16 * 64];    // 4KB

    if (t < 48) s_phys[t] = phys[n0 * 3 + t];
    __syncthreads();

    // layer 1: thread -> node m=t>>4, cols i0..i0+15 (fp32, then bf16 to LDS)
    {
        const int m  = t >> 4;
        const int i0 = (t & 15) * 16;
        const float p0 = s_phys[m*3+0], p1 = s_phys[m*3+1], p2 = s_phys[m*3+2];
        float h[16];
#pragma unroll
        for (int u = 0; u < 4; ++u) {
            const float4 a0 = *(const float4*)&w1[0*HH + i0 + 4*u];
            const float4 a1 = *(const float4*)&w1[1*HH + i0 + 4*u];
            const float4 a2 = *(const float4*)&w1[2*HH + i0 + 4*u];
            const float4 bb = *(const float4*)&b1[i0 + 4*u];
            h[4*u+0] = fmaxf(p0*a0.x + p1*a1.x + p2*a2.x + bb.x, 0.f);
            h[4*u+1] = fmaxf(p0*a0.y + p1*a1.y + p2*a2.y + bb.y, 0.f);
            h[4*u+2] = fmaxf(p0*a0.z + p1*a1.z + p2*a2.z + bb.z, 0.f);
            h[4*u+3] = fmaxf(p0*a0.w + p1*a1.w + p2*a2.w + bb.w, 0.f);
        }
#pragma unroll
        for (int u = 0; u < 2; ++u) {
            short8_t s;
#pragma unroll
            for (int j = 0; j < 8; ++j) s[j] = f2bf(h[8*u + j]);
            *(short8_t*)&s_h1b[m * 256 + ((i0 + 8*u) ^ ((m & 7) << 3))] = s;
        }
    }
    __syncthreads();

    // layer 2: wave wv owns nt = 4wv..4wv+3; A row=lane&15, k=8*(lane>>4)+j
    f32x4_t acc[4];
#pragma unroll
    for (int u = 0; u < 4; ++u) acc[u] = f32x4_t{0.f, 0.f, 0.f, 0.f};
    short8_t af[8];
#pragma unroll
    for (int ks = 0; ks < 8; ++ks)
        af[ks] = *(const short8_t*)&s_h1b[lc * 256 + ((ks*32 + 8*lg) ^ ((lc & 7) << 3))];
#pragma unroll
    for (int u = 0; u < 4; ++u) {
        const int nt = 4 * wv + u;
#pragma unroll
        for (int ks = 0; ks < 8; ++ks) {
            const short8_t bfr = *(const short8_t*)&w2f[(size_t)((ks*16 + nt)*64 + lane) * 8];
            acc[u] = __builtin_amdgcn_mfma_f32_16x16x32_bf16(af[ks], bfr, acc[u], 0, 0, 0);
        }
    }

    // layer 3: lane holds h2 for rows m=4lg+q, col j=nt*16+lc
    float p3[4][2];
#pragma unroll
    for (int q = 0; q < 4; ++q) { p3[q][0] = 0.f; p3[q][1] = 0.f; }
#pragma unroll
    for (int u = 0; u < 4; ++u) {
        const int j = (4*wv + u) * 16 + lc;
        const float b2v = b2[j];
        const float w30 = w3[j*2+0], w31 = w3[j*2+1];
#pragma unroll
        for (int q = 0; q < 4; ++q) {
            const float h2 = fmaxf(acc[u][q] + b2v, 0.f);
            p3[q][0] += h2 * w30; p3[q][1] += h2 * w31;
        }
    }
#pragma unroll
    for (int off = 8; off >= 1; off >>= 1)
#pragma unroll
        for (int q = 0; q < 4; ++q) {
            p3[q][0] += __shfl_xor(p3[q][0], off);
            p3[q][1] += __shfl_xor(p3[q][1], off);
        }
    if (lc == 0)
#pragma unroll
        for (int q = 0; q < 4; ++q) {
            s_red[wv][4*lg + q][0] = p3[q][0];
            s_red[wv][4*lg + q][1] = p3[q][1];
        }
    __syncthreads();

    if (t < 32) {
        const int m = t >> 1, d = t & 1;
        const float raw = s_red[0][m][d] + s_red[1][m][d] + s_red[2][m][d] + s_red[3][m][d] + b3[d];
        s_kxw[m][d] = (d == 0) ? sigmoidf_(raw) * 0.25f + 0.005f
                               : sigmoidf_(raw - 3.f) * 1.2f;
    }
    __syncthreads();

    // IRF: thread -> node nd=t>>4, taps (t&15)+16u
    {
        const int nd = t >> 4, l = t & 15;
        const float k = s_kxw[nd][0], xw = s_kxw[nd][1];
        const float delay = k * xw;
        const float tau   = fmaxf(k * (1.f - xw), 0.5f * DTF);
        float hv[4]; float s = 0.f;
#pragma unroll
        for (int u = 0; u < 4; ++u) {
            const float tf = (l + 16*u) * DTF;
            hv[u] = (tf >= delay) ? __expf(-(tf - delay) / tau) / tau : 0.f;
            s += hv[u];
        }
#pragma unroll
        for (int off = 8; off >= 1; off >>= 1) s += __shfl_xor(s, off);
        const float inv = 1.f / (s + 1e-8f);
        float* drow = irf + (size_t)(n0 + nd) * WW;
#pragma unroll
        for (int u = 0; u < 4; ++u) {
            const float v = hv[u] * inv;
            drow[l + 16*u]        = v;
            s_irf[nd*64 + l + 16*u] = v;
        }
    }
    __syncthreads();

    // conv B-frag table: irfB[n][p][L][j] = rfz[(L&15) - 8*(L>>4) - j + 16 + 32p]
    {
        const int nd = t >> 4, lb = t & 15;
        const float* sr = &s_irf[nd * 64];
        short* dst = irfB + (size_t)(n0 + nd) * 1536;
#pragma unroll
        for (int li = 0; li < 4; ++li) {
            const int L = 4*lb + li;
            const int Llc = L & 15, Llg = L >> 4;
#pragma unroll
            for (int p = 0; p < 3; ++p) {
                short8_t v;
#pragma unroll
                for (int j = 0; j < 8; ++j) {
                    const int idx = Llc - 8*Llg - j + 16 + 32*p;
                    v[j] = f2bf((idx >= 0 && idx < 64) ? sr[idx & 63] : 0.f);
                }
                *(short8_t*)&dst[(size_t)(p*64 + L) * 8] = v;
            }
        }
    }
}

// ================= MFMA conv machinery =================
#define LROW 1152   // 80-elem zero prologue + 1024 row, shorts, swizzled

__device__ __forceinline__ void zero_prologue(short* sab, int tid) {
    if (tid < 10) {
        short8_t z = {0,0,0,0,0,0,0,0};
        *(short8_t*)&sab[swz(8 * tid)] = z;
    }
}

__device__ __forceinline__ void load16(const float* __restrict__ src, int tid, float (&a)[16]) {
#pragma unroll
    for (int u = 0; u < 4; ++u) {
        const float4 v = *(const float4*)&src[16 * tid + 4 * u];
        a[4*u+0] = v.x; a[4*u+1] = v.y; a[4*u+2] = v.z; a[4*u+3] = v.w;
    }
}

__device__ __forceinline__ void stage16(short* sab, const float (&a)[16], int tid) {
#pragma unroll
    for (int u = 0; u < 2; ++u) {
        short8_t s;
#pragma unroll
        for (int j = 0; j < 8; ++j) s[j] = f2bf(a[8*u + j]);
        *(short8_t*)&sab[swz(80 + 16 * tid + 8 * u)] = s;
    }
}

__device__ __forceinline__ void load_bfrags(const short* __restrict__ irfB, int n,
                                            int tid, short8_t (&bf)[3]) {
#pragma unroll
    for (int p = 0; p < 3; ++p)
        bf[p] = *(const short8_t*)&irfB[(size_t)n * 1536 + (size_t)(p*64 + tid) * 8];
}

// 12 MFMAs accumulating into acc[S]; EB = 80 + 16*(lane&15) + 8*(lane>>4)
__device__ __forceinline__ void conv_mfma3(const short* sab, const short8_t (&bf)[3],
                                           int EB, f32x4_t (&acc)[4]) {
#pragma unroll
    for (int S = 0; S < 4; ++S) {
#pragma unroll
        for (int p = 0; p < 3; ++p) {
            const short8_t af = *(const short8_t*)&sab[swz(EB + 256 * S - 16 * (2 * p + 1))];
            acc[S] = __builtin_amdgcn_mfma_f32_16x16x32_bf16(af, bf[p], acc[S], 0, 0, 0);
        }
    }
}

// ---------------- leaves 2048..5460 + L6-internal 1365..2047 ----------------
__global__ __launch_bounds__(256) void route_lf6_mfma(
    const float* __restrict__ x, const short* __restrict__ irfB,
    float* __restrict__ out)
{
    const int wid = threadIdx.x >> 6;
    const int tid = threadIdx.x & 63;
    const int r   = blockIdx.x * 4 + wid;

    const int lc = tid & 15, lg = tid >> 4;
    const int EB = 80 + 16 * lc + 8 * lg;

    __shared__ __align__(16) short s_a[4][LROW];
    short* sab = s_a[wid];
    zero_prologue(sab, tid);

    float a16[16];
    short8_t bf[3];

    if (r < 1366) {
        const int b = r & 1;
        const int n = __builtin_amdgcn_readfirstlane(1365 + (r >> 1));
        const size_t rowb = ((size_t)b * NN + n) * TT;
        const int c0 = 4 * n + 1;

        f32x4_t accD[4];
#pragma unroll
        for (int S = 0; S < 4; ++S)
#pragma unroll
            for (int q = 0; q < 4; ++q)
                accD[S][q] = x[rowb + 256 * S + 64 * lg + 16 * q + lc];

#pragma unroll 1
        for (int e = 0; e < 4; ++e) {
            const int c = c0 + e;
            if (c < NN) {            // node 2047: 4th child 8192 OOB
                const size_t crow = ((size_t)b * NN + c) * TT;
                load16(x + crow, tid, a16);
                stage16(sab, a16, tid);
                load_bfrags(irfB, c, tid, bf);
                f32x4_t accT[4];
#pragma unroll
                for (int S = 0; S < 4; ++S) accT[S] = f32x4_t{0.f, 0.f, 0.f, 0.f};
                conv_mfma3(sab, bf, EB, accT);
#pragma unroll
                for (int S = 0; S < 4; ++S) {
#pragma unroll
                    for (int q = 0; q < 4; ++q)
                        out[crow + 256 * S + 64 * lg + 16 * q + lc] = accT[S][q];
                    accD[S] += accT[S];
                }
            }
        }

#pragma unroll
        for (int S = 0; S < 4; ++S)
#pragma unroll
            for (int q = 0; q < 4; ++q)
                sab[swz(80 + 256 * S + 64 * lg + 16 * q + lc)] = f2bf(accD[S][q]);

        load_bfrags(irfB, n, tid, bf);
        f32x4_t accF[4];
#pragma unroll
        for (int S = 0; S < 4; ++S) accF[S] = f32x4_t{0.f, 0.f, 0.f, 0.f};
        conv_mfma3(sab, bf, EB, accF);
#pragma unroll
        for (int S = 0; S < 4; ++S)
#pragma unroll
            for (int q = 0; q < 4; ++q)
                out[rowb + 256 * S + 64 * lg + 16 * q + lc] = accF[S][q];
    } else {
        const int idx = r - 1366;
        const int b = idx & 1;
        const int n = __builtin_amdgcn_readfirstlane(2048 + (idx >> 1));
        const size_t rowb = ((size_t)b * NN + n) * TT;

        load16(x + rowb, tid, a16);
        stage16(sab, a16, tid);
        load_bfrags(irfB, n, tid, bf);
        f32x4_t accF[4];
#pragma unroll
        for (int S = 0; S < 4; ++S) accF[S] = f32x4_t{0.f, 0.f, 0.f, 0.f};
        conv_mfma3(sab, bf, EB, accF);
#pragma unroll
        for (int S = 0; S < 4; ++S)
#pragma unroll
            for (int q = 0; q < 4; ++q)
                out[rowb + 256 * S + 64 * lg + 16 * q + lc] = accF[S][q];
    }
}

// ---------------- L5 (341..1364) ----------------
__global__ __launch_bounds__(256) void route_mid_mfma(
    const float* __restrict__ x, const short* __restrict__ irfB,
    float* __restrict__ out)
{
    const int wid = threadIdx.x >> 6;
    const int tid = threadIdx.x & 63;
    const int r   = blockIdx.x * 4 + wid;

    const int lc = tid & 15, lg = tid >> 4;
    const int EB = 80 + 16 * lc + 8 * lg;

    __shared__ __align__(16) short s_a[4][LROW];
    short* sab = s_a[wid];
    zero_prologue(sab, tid);

    const int b = r & 1;
    const int n = __builtin_amdgcn_readfirstlane(341 + (r >> 1));
    const size_t rowb = ((size_t)b * NN + n) * TT;
    const int c0 = 4 * n + 1;

    float a16[16];
#pragma unroll
    for (int u = 0; u < 4; ++u) {
        float4 v = *(const float4*)&x[rowb + 16 * tid + 4 * u];
#pragma unroll
        for (int e = 0; e < 4; ++e) {
            const float4 w = *(const float4*)&out[((size_t)b * NN + c0 + e) * TT + 16 * tid + 4 * u];
            v.x += w.x; v.y += w.y; v.z += w.z; v.w += w.w;
        }
        a16[4*u+0] = v.x; a16[4*u+1] = v.y; a16[4*u+2] = v.z; a16[4*u+3] = v.w;
    }
    stage16(sab, a16, tid);

    short8_t bf[3];
    load_bfrags(irfB, n, tid, bf);
    f32x4_t accF[4];
#pragma unroll
    for (int S = 0; S < 4; ++S) accF[S] = f32x4_t{0.f, 0.f, 0.f, 0.f};
    conv_mfma3(sab, bf, EB, accF);
#pragma unroll
    for (int S = 0; S < 4; ++S)
#pragma unroll
        for (int q = 0; q < 4; ++q)
            out[rowb + 256 * S + 64 * lg + 16 * q + lc] = accF[S][q];
}

// ================= scalar fp32 tail =================
__device__ __forceinline__ void load_rf(const float* __restrict__ irf, int n, float (&rf)[WW]) {
    const float* irp = irf + (size_t)n * WW;
#pragma unroll
    for (int i = 0; i < WW / 4; ++i) {
        const float4 f = *(const float4*)&irp[4 * i];
        rf[4*i+0] = f.x; rf[4*i+1] = f.y; rf[4*i+2] = f.z; rf[4*i+3] = f.w;
    }
}

__device__ __forceinline__ void wave_conv16(const float (&a)[16], const float (&rf)[WW],
                                            float (&y)[16], int tid)
{
#pragma unroll
    for (int j = 0; j < 16; ++j) y[j] = 0.0f;
#pragma unroll
    for (int m = 0; m < 16; ++m)
#pragma unroll
        for (int j = m; j < 16; ++j)
            y[j] += rf[j - m] * a[m];
#pragma unroll
    for (int d = 1; d <= 4; ++d) {
        float h[16];
#pragma unroll
        for (int m = 0; m < 16; ++m) {
            const float ha = __shfl(a[m], tid - d);
            h[m] = (tid >= d) ? ha : 0.0f;
        }
        if (d < 4) {
#pragma unroll
            for (int m = 0; m < 16; ++m)
#pragma unroll
                for (int j = 0; j < 16; ++j)
                    y[j] += rf[j + 16 * d - m] * h[m];
        } else {
#pragma unroll
            for (int m = 1; m < 16; ++m)
#pragma unroll
                for (int j = 0; j < m; ++j)
                    y[j] += rf[j + WW - m] * h[m];
        }
    }
}

__global__ __launch_bounds__(256) void route_tail3(
    const float* __restrict__ x, const float* __restrict__ irf,
    float* __restrict__ out, int top_base)
{
    const int wid = threadIdx.x >> 6;
    const int tid = threadIdx.x & 63;
    const int b   = blockIdx.x & 1;
    const int p   = top_base + (int)(blockIdx.x >> 1);

    __shared__ __align__(16) float s_ch[4][TT];

    const int cw = 4 * p + 1 + wid;
    const size_t crow = ((size_t)b * NN + cw) * TT;
    const int loc = tid * 16;

#pragma unroll
    for (int u = 0; u < 4; ++u)
        *(float4*)&s_ch[wid][loc + 4 * u] = *(const float4*)&x[crow + loc + 4 * u];

    float rf[WW], a[16], y[16];

#pragma unroll 1
    for (int k = 0; k < 4; ++k) {
        const int g = 4 * cw + 1 + k;
        const size_t grow = ((size_t)b * NN + g) * TT;
#pragma unroll
        for (int u = 0; u < 4; ++u) {
            float4 v = *(const float4*)&x[grow + loc + 4 * u];
#pragma unroll
            for (int e = 0; e < 4; ++e) {
                const float4 w = *(const float4*)&out[((size_t)b * NN + (4 * g + 1 + e)) * TT + loc + 4 * u];
                v.x += w.x; v.y += w.y; v.z += w.z; v.w += w.w;
            }
            a[4*u+0] = v.x; a[4*u+1] = v.y; a[4*u+2] = v.z; a[4*u+3] = v.w;
        }
        load_rf(irf, g, rf);
        wave_conv16(a, rf, y, tid);
#pragma unroll
        for (int u = 0; u < 4; ++u) {
            *(float4*)&out[grow + loc + 4 * u] = make_float4(y[4*u+0], y[4*u+1], y[4*u+2], y[4*u+3]);
#pragma unroll
            for (int e = 0; e < 4; ++e) s_ch[wid][loc + 4*u + e] += y[4*u + e];
        }
    }

#pragma unroll
    for (int u = 0; u < 4; ++u) {
        const float4 v = *(const float4*)&s_ch[wid][loc + 4 * u];
        a[4*u+0] = v.x; a[4*u+1] = v.y; a[4*u+2] = v.z; a[4*u+3] = v.w;
    }
    load_rf(irf, cw, rf);
    wave_conv16(a, rf, y, tid);
#pragma unroll
    for (int u = 0; u < 4; ++u) {
        const float4 f = make_float4(y[4*u+0], y[4*u+1], y[4*u+2], y[4*u+3]);
        *(float4*)&out[crow + loc + 4 * u] = f;
        *(float4*)&s_ch[wid][loc + 4 * u]  = f;
    }

    __syncthreads();

    if (wid == 0) {
        const size_t prow = ((size_t)b * NN + p) * TT;
#pragma unroll
        for (int u = 0; u < 4; ++u) {
            float4 v = *(const float4*)&x[prow + loc + 4 * u];
#pragma unroll
            for (int w2 = 0; w2 < 4; ++w2) {
                const float4 cc = *(const float4*)&s_ch[w2][loc + 4 * u];
                v.x += cc.x; v.y += cc.y; v.z += cc.z; v.w += cc.w;
            }
            a[4*u+0] = v.x; a[4*u+1] = v.y; a[4*u+2] = v.z; a[4*u+3] = v.w;
        }
        load_rf(irf, p, rf);
        wave_conv16(a, rf, y, tid);
#pragma unroll
        for (int u = 0; u < 4; ++u)
            *(float4*)&out[prow + loc + 4 * u] = make_float4(y[4*u+0], y[4*u+1], y[4*u+2], y[4*u+3]);
    }
}

__global__ __launch_bounds__(256) void route_tail2(
    const float* __restrict__ x, const float* __restrict__ irf,
    float* __restrict__ out)
{
    const int wid = threadIdx.x >> 6;
    const int tid = threadIdx.x & 63;
    const int b   = blockIdx.x;

    __shared__ __align__(16) float s_ch[4][TT];

    const int cw = 1 + wid;
    const size_t crow = ((size_t)b * NN + cw) * TT;
    const int loc = tid * 16;

    float rf[WW], a[16], y[16];

#pragma unroll
    for (int u = 0; u < 4; ++u) {
        float4 v = *(const float4*)&x[crow + loc + 4 * u];
#pragma unroll
        for (int e = 0; e < 4; ++e) {
            const float4 w = *(const float4*)&out[((size_t)b * NN + (4 * cw + 1 + e)) * TT + loc + 4 * u];
            v.x += w.x; v.y += w.y; v.z += w.z; v.w += w.w;
        }
        a[4*u+0] = v.x; a[4*u+1] = v.y; a[4*u+2] = v.z; a[4*u+3] = v.w;
    }
    load_rf(irf, cw, rf);
    wave_conv16(a, rf, y, tid);
#pragma unroll
    for (int u = 0; u < 4; ++u) {
        const float4 f = make_float4(y[4*u+0], y[4*u+1], y[4*u+2], y[4*u+3]);
        *(float4*)&out[crow + loc + 4 * u] = f;
        *(float4*)&s_ch[wid][loc + 4 * u]  = f;
    }

    __syncthreads();

    if (wid == 0) {
        const size_t prow = (size_t)b * NN * TT;
#pragma unroll
        for (int u = 0; u < 4; ++u) {
            float4 v = *(const float4*)&x[prow + loc + 4 * u];
#pragma unroll
            for (int w2 = 0; w2 < 4; ++w2) {
                const float4 cc = *(const float4*)&s_ch[w2][loc + 4 * u];
                v.x += cc.x; v.y += cc.y; v.z += cc.z; v.w += cc.w;
            }
            a[4*u+0] = v.x; a[4*u+1] = v.y; a[4*u+2] = v.z; a[4*u+3] = v.w;
        }
        load_rf(irf, 0, rf);
        wave_conv16(a, rf, y, tid);
#pragma unroll
        for (int u = 0; u < 4; ++u)
            *(float4*)&out[prow + loc + 4 * u] = make_float4(y[4*u+0], y[4*u+1], y[4*u+2], y[4*u+3]);
    }
}

extern "C" void kernel_launch(void* const* d_in, const int* in_sizes, int n_in,
                              void* d_out, int out_size, void* d_ws, size_t ws_size,
                              hipStream_t stream) {
    const float* x    = (const float*)d_in[0];
    const float* phys = (const float*)d_in[1];
    const float* w1   = (const float*)d_in[2];
    const float* b1   = (const float*)d_in[3];
    const float* w2   = (const float*)d_in[4];
    const float* b2   = (const float*)d_in[5];
    const float* w3   = (const float*)d_in[6];
    const float* b3   = (const float*)d_in[7];
    // d_in[8] = parent, d_in[9] = depth: fixed 4-ary heap tree (children 4n+1..4n+4)

    float* out = (float*)d_out;
    // ws layout: irf fp32 [0,2MB) | w2f bf16 [2MB,+128KB) | irfB [4MB,+24MB)
    float* irf  = (float*)d_ws;
    short* w2f  = (short*)((char*)d_ws + (2u << 20));
    short* irfB = (short*)((char*)d_ws + (4u << 20));

    w2bf_kernel<<<32, 256, 0, stream>>>(w2, w2f);
    mlp_mfma<<<512, 256, 0, stream>>>(phys, w1, b1, w2f, b2, w3, b3, irf, irfB);

    // 1) L6-int (1366 tasks, stores children 5461..8191) + leaves 2048..5460
    route_lf6_mfma<<<2048, 256, 0, stream>>>(x, irfB, out);
    // 2) L5: 1024 x 2 = 2048 tasks
    route_mid_mfma<<<512, 256, 0, stream>>>(x, irfB, out);
    // 3) L4+L3+L2 fused per L2 node
    route_tail3<<<32, 256, 0, stream>>>(x, irf, out, 5);
    // 4) L1+L0
    route_tail2<<<2, 256, 0, stream>>>(x, irf, out);
}